// Round 1
// baseline (2232.664 us; speedup 1.0000x reference)
//
#include <hip/hip_runtime.h>
#include <hip/hip_bf16.h>

// Problem constants (from reference)
#define NUM_EXPERTS 8
#define HIDDEN      2048
#define INTER       6144
#define TOKENS      1024   // per expert

typedef __bf16 bf16x8 __attribute__((ext_vector_type(8)));
typedef __bf16 bf16x4 __attribute__((ext_vector_type(4)));
typedef float  floatx4 __attribute__((ext_vector_type(4)));

// ---------- async global->LDS, width 16 (m97's key instruction) ----------
__device__ __forceinline__ void load_lds16(const void* gp, void* lp) {
    __builtin_amdgcn_global_load_lds(
        (__attribute__((address_space(1))) void*)(gp),
        (__attribute__((address_space(3))) void*)(lp),
        16, 0, 0);
}

// ---------- fp32 -> bf16 convert (tokens; layout unchanged) ----------
__global__ void cvt_f32_bf16(const float* __restrict__ in, __bf16* __restrict__ out, size_t n) {
    size_t i = ((size_t)blockIdx.x * blockDim.x + threadIdx.x) * 4;
    if (i + 3 < n) {
        float4 v = *(const float4*)(in + i);
        bf16x4 o;
        o[0] = (__bf16)v.x; o[1] = (__bf16)v.y; o[2] = (__bf16)v.z; o[3] = (__bf16)v.w;
        *(bf16x4*)(out + i) = o;
    }
}

// ---------- fp32 [B][R][C] -> bf16 [B][C][R] transpose-convert ----------
// 64x64 tile, 256 threads. LDS pitch 66 (bf16) keeps reads/writes <=2-way
// bank-aliased (free per m136).
__global__ void transpose_cvt(const float* __restrict__ in, __bf16* __restrict__ out,
                              int R, int C) {
    __shared__ __bf16 tile[64][66];
    const int tx = threadIdx.x & 63;
    const int ty = threadIdx.x >> 6;   // 0..3
    const int c0 = blockIdx.x * 64;
    const int r0 = blockIdx.y * 64;
    const float* inb = in + (size_t)blockIdx.z * (size_t)R * (size_t)C;
    __bf16* outb = out + (size_t)blockIdx.z * (size_t)R * (size_t)C;
    #pragma unroll
    for (int r = ty; r < 64; r += 4)
        tile[r][tx] = (__bf16)inb[(size_t)(r0 + r) * C + (c0 + tx)];
    __syncthreads();
    #pragma unroll
    for (int cc = ty; cc < 64; cc += 4)
        outb[(size_t)(c0 + cc) * R + (r0 + tx)] = tile[tx][cc];
}

// ---------- silu(gate)*up : gu [rows][2I] bf16 -> h [rows][I] bf16 ----------
__global__ void silu_mul(const __bf16* __restrict__ gu, __bf16* __restrict__ h) {
    size_t lin = ((size_t)blockIdx.x * blockDim.x + threadIdx.x) * 4; // over rows*I
    size_t row = lin / INTER;
    int    i   = (int)(lin % INTER);
    bf16x4 g4 = *(const bf16x4*)(gu + row * (2 * INTER) + i);
    bf16x4 u4 = *(const bf16x4*)(gu + row * (2 * INTER) + INTER + i);
    bf16x4 o;
    #pragma unroll
    for (int j = 0; j < 4; ++j) {
        float g = (float)g4[j];
        float u = (float)u4[j];
        float s = g / (1.f + __expf(-g));
        o[j] = (__bf16)(s * u);
    }
    *(bf16x4*)(h + row * INTER + i) = o;
}

// ---------- bf16 GEMM, C = A * Bt^T per expert (m97 structure) ----------
// A: [M][K] k-contig, Bt: [N][K] k-contig, C: [M][N].
// 128x128 tile, BK=32, 256 threads = 4 waves in 2x2, each wave 64x64 via
// 4x4 mfma_f32_16x16x32_bf16. Staging via global_load_lds width=16.
#define BM 128
#define BN 128
#define BK 32

template <bool OUT_BF16>
__global__ void gemm_bt(const __bf16* __restrict__ A, const __bf16* __restrict__ Bt,
                        void* __restrict__ C, int M, int N, int K,
                        size_t sA, size_t sB, size_t sC) {
    __shared__ alignas(16) __bf16 As[BM * BK];
    __shared__ alignas(16) __bf16 Bs[BN * BK];

    const int tid  = threadIdx.x;
    const int wid  = tid >> 6;
    const int lane = tid & 63;
    const int lr   = lane & 15;   // fragment row/col within 16
    const int lh   = lane >> 4;   // k-quad: k = lh*8 + j
    const int m0   = blockIdx.y * BM;
    const int n0   = blockIdx.x * BN;

    const __bf16* Ae = A  + (size_t)blockIdx.z * sA;
    const __bf16* Be = Bt + (size_t)blockIdx.z * sB;

    const int wm = (wid >> 1) * 64;
    const int wn = (wid & 1) * 64;

    floatx4 acc[4][4];
    #pragma unroll
    for (int i = 0; i < 4; ++i)
        #pragma unroll
        for (int j = 0; j < 4; ++j)
            acc[i][j] = floatx4{0.f, 0.f, 0.f, 0.f};

    const int segBase = wid * 2048;  // byte segment of the tile this wave stages

    for (int kt = 0; kt < K; kt += BK) {
        // ---- stage A tile [BM][BK] (8192 B): 2 calls/wave x 1024 B ----
        #pragma unroll
        for (int c = 0; c < 2; ++c) {
            int L    = segBase + c * 1024 + lane * 16; // linear byte in tile
            int row  = L >> 6;                          // 64 B per row (32 bf16)
            int colb = L & 63;
            const char* gp = (const char*)(Ae + (size_t)(m0 + row) * K + kt) + colb;
            load_lds16(gp, (char*)As + segBase + c * 1024);
        }
        // ---- stage B tile [BN][BK] ----
        #pragma unroll
        for (int c = 0; c < 2; ++c) {
            int L    = segBase + c * 1024 + lane * 16;
            int row  = L >> 6;
            int colb = L & 63;
            const char* gp = (const char*)(Be + (size_t)(n0 + row) * K + kt) + colb;
            load_lds16(gp, (char*)Bs + segBase + c * 1024);
        }
        __syncthreads();   // compiler drains vmcnt before s_barrier

        bf16x8 a[4], b[4];
        #pragma unroll
        for (int mt = 0; mt < 4; ++mt)
            a[mt] = *(const bf16x8*)&As[(wm + mt * 16 + lr) * BK + lh * 8];
        #pragma unroll
        for (int nt = 0; nt < 4; ++nt)
            b[nt] = *(const bf16x8*)&Bs[(wn + nt * 16 + lr) * BK + lh * 8];

        #pragma unroll
        for (int mt = 0; mt < 4; ++mt)
            #pragma unroll
            for (int nt = 0; nt < 4; ++nt)
                acc[mt][nt] = __builtin_amdgcn_mfma_f32_16x16x32_bf16(
                    a[mt], b[nt], acc[mt][nt], 0, 0, 0);
        __syncthreads();
    }

    // ---- epilogue: C/D layout col=lane&15, row=(lane>>4)*4+reg ----
    if constexpr (OUT_BF16) {
        __bf16* Ce = (__bf16*)C + (size_t)blockIdx.z * sC;
        #pragma unroll
        for (int mt = 0; mt < 4; ++mt)
            #pragma unroll
            for (int nt = 0; nt < 4; ++nt)
                #pragma unroll
                for (int v = 0; v < 4; ++v) {
                    int r = m0 + wm + mt * 16 + lh * 4 + v;
                    int c = n0 + wn + nt * 16 + lr;
                    Ce[(size_t)r * N + c] = (__bf16)acc[mt][nt][v];
                }
    } else {
        float* Ce = (float*)C + (size_t)blockIdx.z * sC;
        #pragma unroll
        for (int mt = 0; mt < 4; ++mt)
            #pragma unroll
            for (int nt = 0; nt < 4; ++nt)
                #pragma unroll
                for (int v = 0; v < 4; ++v) {
                    int r = m0 + wm + mt * 16 + lh * 4 + v;
                    int c = n0 + wn + nt * 16 + lr;
                    Ce[(size_t)r * N + c] = acc[mt][nt][v];
                }
    }
}

extern "C" void kernel_launch(void* const* d_in, const int* in_sizes, int n_in,
                              void* d_out, int out_size, void* d_ws, size_t ws_size,
                              hipStream_t stream) {
    const float* x   = (const float*)d_in[0];  // [E*T, D]
    const float* wgu = (const float*)d_in[1];  // [E, D, 2I]
    const float* wd  = (const float*)d_in[2];  // [E, I, D]
    float* out = (float*)d_out;                // [E*T, D] fp32

    constexpr size_t E = NUM_EXPERTS, T = TOKENS, D = HIDDEN, I = INTER;

    // Workspace layout (bytes), with lifetime-based aliasing:
    //   [0, 201326592)            : GU  (E*T*2I bf16)  -> later reused as WdT (E*D*I bf16)
    //   [201326592, 637534208)    : Xb (E*T*D bf16) + WguT (E*2I*D bf16)
    //                               H (E*T*I bf16) aliases this region after GEMM1.
    char* ws = (char*)d_ws;
    __bf16* GU   = (__bf16*)ws;                          // 201,326,592 B
    __bf16* WdT  = (__bf16*)ws;                          // aliases GU (after silu)
    char*   regA = ws + 201326592;
    __bf16* Xb   = (__bf16*)regA;                        // 33,554,432 B
    __bf16* WguT = (__bf16*)(regA + 33554432);           // 402,653,184 B
    __bf16* H    = (__bf16*)regA;                        // 100,663,296 B (aliases Xb+WguT head)

    // 1) tokens fp32 -> bf16 (16.7M elems)
    cvt_f32_bf16<<<dim3(16384), dim3(256), 0, stream>>>(x, Xb, E * T * D);

    // 2) w_gate_up [E][D][2I] -> WguT [E][2I][D] bf16
    transpose_cvt<<<dim3(2 * I / 64, D / 64, E), dim3(256), 0, stream>>>(wgu, WguT, (int)D, (int)(2 * I));

    // 3) GEMM1: GU[e] = Xb[e] (T x D) * WguT[e]^T  -> [T x 2I] bf16
    gemm_bt<true><<<dim3(2 * I / BN, T / BM, E), dim3(256), 0, stream>>>(
        Xb, WguT, GU, (int)T, (int)(2 * I), (int)D, T * D, 2 * I * D, T * 2 * I);

    // 4) H = silu(gate) * up   (E*T*I elems, 4/thread)
    silu_mul<<<dim3((unsigned)(E * T * I / 4 / 256)), dim3(256), 0, stream>>>(GU, H);

    // 5) w_down [E][I][D] -> WdT [E][D][I] bf16   (reuses GU region)
    transpose_cvt<<<dim3(D / 64, I / 64, E), dim3(256), 0, stream>>>(wd, WdT, (int)I, (int)D);

    // 6) GEMM2: out[e] = H[e] (T x I) * WdT[e]^T -> [T x D] fp32
    gemm_bt<false><<<dim3(D / BN, T / BM, E), dim3(256), 0, stream>>>(
        H, WdT, out, (int)T, (int)D, (int)I, T * I, D * I, T * D);
}

// Round 2
// 2142.460 us; speedup vs baseline: 1.0421x; 1.0421x over previous
//
#include <hip/hip_runtime.h>
#include <hip/hip_bf16.h>

// Problem constants (from reference)
#define NUM_EXPERTS 8
#define HIDDEN      2048
#define INTER       6144
#define TOKENS      1024   // per expert

typedef __bf16 bf16x8 __attribute__((ext_vector_type(8)));
typedef __bf16 bf16x4 __attribute__((ext_vector_type(4)));
typedef float  floatx4 __attribute__((ext_vector_type(4)));

// ---------- async global->LDS, width 16 ----------
__device__ __forceinline__ void load_lds16(const void* gp, void* lp) {
    __builtin_amdgcn_global_load_lds(
        (__attribute__((address_space(1))) void*)(gp),
        (__attribute__((address_space(3))) void*)(lp),
        16, 0, 0);
}

// ---------- fp32 -> bf16 convert (tokens; layout unchanged) ----------
__global__ void cvt_f32_bf16(const float* __restrict__ in, __bf16* __restrict__ out, size_t n) {
    size_t i = ((size_t)blockIdx.x * blockDim.x + threadIdx.x) * 4;
    if (i + 3 < n) {
        float4 v = *(const float4*)(in + i);
        bf16x4 o;
        o[0] = (__bf16)v.x; o[1] = (__bf16)v.y; o[2] = (__bf16)v.z; o[3] = (__bf16)v.w;
        *(bf16x4*)(out + i) = o;
    }
}

// ---------- fp32 [B][R][C] -> bf16 [B][C][R] transpose-convert, vectorized ----------
// 64x64 tile, 256 threads. Reads: float4 (16B/lane, coalesced). Writes: bf16x8
// (16B/lane, contiguous in 128B runs of 8 lanes). LDS: pitch-64 bf16 tile with
// XOR swizzle c' = c ^ 8*((r>>3)&7): phase-2 reads conflict-free (bijective
// bank cover per instruction), phase-1 writes 4-way (~free at this scale).
__global__ void transpose_cvt(const float* __restrict__ in, __bf16* __restrict__ out,
                              int R, int C) {
    __shared__ __bf16 tile[64 * 64];
    const int tid = threadIdx.x;
    const int c0 = blockIdx.x * 64;
    const int r0 = blockIdx.y * 64;
    const float* inb = in + (size_t)blockIdx.z * (size_t)R * (size_t)C;
    __bf16* outb = out + (size_t)blockIdx.z * (size_t)R * (size_t)C;

    // phase 1: global float4 -> cvt -> LDS (swizzled)
    const int ci = (tid & 15) * 4;   // col within tile, 4-aligned
    const int rr = tid >> 4;         // 0..15
    #pragma unroll
    for (int p = 0; p < 4; ++p) {
        int r = rr + 16 * p;
        float4 v = *(const float4*)&inb[(size_t)(r0 + r) * C + (c0 + ci)];
        bf16x4 o;
        o[0] = (__bf16)v.x; o[1] = (__bf16)v.y; o[2] = (__bf16)v.z; o[3] = (__bf16)v.w;
        int csw = ci ^ (8 * ((r >> 3) & 7));
        *(bf16x4*)&tile[r * 64 + csw] = o;
    }
    __syncthreads();

    // phase 2: LDS (swizzled scalar reads) -> bf16x8 global store
    const int cl = tid >> 3;           // 0..31
    const int rb = (tid & 7) * 8;      // row-block base
    #pragma unroll
    for (int q = 0; q < 2; ++q) {
        int c = cl + 32 * q;
        bf16x8 o;
        #pragma unroll
        for (int j = 0; j < 8; ++j) {
            int r = rb + j;
            o[j] = tile[r * 64 + (c ^ (8 * ((r >> 3) & 7)))];
        }
        *(bf16x8*)&outb[(size_t)(c0 + c) * R + (r0 + rb)] = o;
    }
}

// ---------- GEMM1 fused with silu: H = silu(X*Wg^T) * (X*Wu^T) ----------
// A: Xb [T][D] k-contig. Bt: WguT [2I][D] k-contig (rows 0..I-1 = gate cols,
// I..2I-1 = up cols). Block tile: M=128, N=64 (gate) + the matching 64 up
// cols. Same LDS (16KB), same acc budget (64 AGPR), same MFMA/staging ratio
// as the plain 128x128 gemm — fusion is structurally free.
#define BM 128
#define BK 32

__global__ void gemm1_silu(const __bf16* __restrict__ A, const __bf16* __restrict__ Bt,
                           __bf16* __restrict__ H) {
    __shared__ alignas(16) __bf16 As[BM * BK];    // 8 KB
    __shared__ alignas(16) __bf16 Bs[128 * BK];   // 8 KB: rows 0..63 gate, 64..127 up

    const int tid  = threadIdx.x;
    const int wid  = tid >> 6;
    const int lane = tid & 63;
    const int lr   = lane & 15;
    const int lh   = lane >> 4;
    const int m0   = blockIdx.y * BM;
    const int n0   = blockIdx.x * 64;
    const size_t z = blockIdx.z;

    const __bf16* Ae = A  + z * (size_t)(TOKENS * HIDDEN);
    const __bf16* Be = Bt + z * (size_t)(2 * INTER * HIDDEN);

    const int wm = (wid >> 1) * 64;
    const int wn = (wid & 1) * 32;

    floatx4 accg[4][2], accu[4][2];
    #pragma unroll
    for (int i = 0; i < 4; ++i)
        #pragma unroll
        for (int j = 0; j < 2; ++j) {
            accg[i][j] = floatx4{0.f, 0.f, 0.f, 0.f};
            accu[i][j] = floatx4{0.f, 0.f, 0.f, 0.f};
        }

    const int segBase = wid * 2048;

    for (int kt = 0; kt < HIDDEN; kt += BK) {
        // A tile [128][32]
        #pragma unroll
        for (int c = 0; c < 2; ++c) {
            int L    = segBase + c * 1024 + lane * 16;
            int row  = L >> 6;
            int colb = L & 63;
            const char* gp = (const char*)(Ae + (size_t)(m0 + row) * HIDDEN + kt) + colb;
            load_lds16(gp, (char*)As + segBase + c * 1024);
        }
        // B tile [128][32]: tile row rr<64 -> WguT row n0+rr (gate),
        //                   rr>=64 -> WguT row INTER+n0+(rr-64) (up)
        #pragma unroll
        for (int c = 0; c < 2; ++c) {
            int L    = segBase + c * 1024 + lane * 16;
            int rr   = L >> 6;
            int colb = L & 63;
            int grow = (rr < 64) ? (n0 + rr) : (INTER + n0 + (rr - 64));
            const char* gp = (const char*)(Be + (size_t)grow * HIDDEN + kt) + colb;
            load_lds16(gp, (char*)Bs + segBase + c * 1024);
        }
        __syncthreads();

        bf16x8 a[4], bg[2], bu[2];
        #pragma unroll
        for (int mt = 0; mt < 4; ++mt)
            a[mt] = *(const bf16x8*)&As[(wm + mt * 16 + lr) * BK + lh * 8];
        #pragma unroll
        for (int nt = 0; nt < 2; ++nt) {
            bg[nt] = *(const bf16x8*)&Bs[(wn + nt * 16 + lr) * BK + lh * 8];
            bu[nt] = *(const bf16x8*)&Bs[(64 + wn + nt * 16 + lr) * BK + lh * 8];
        }

        #pragma unroll
        for (int mt = 0; mt < 4; ++mt)
            #pragma unroll
            for (int nt = 0; nt < 2; ++nt) {
                accg[mt][nt] = __builtin_amdgcn_mfma_f32_16x16x32_bf16(
                    a[mt], bg[nt], accg[mt][nt], 0, 0, 0);
                accu[mt][nt] = __builtin_amdgcn_mfma_f32_16x16x32_bf16(
                    a[mt], bu[nt], accu[mt][nt], 0, 0, 0);
            }
        __syncthreads();
    }

    // epilogue: h = silu(g)*u, write H [T][I] bf16
    __bf16* He = H + z * (size_t)(TOKENS * INTER);
    #pragma unroll
    for (int mt = 0; mt < 4; ++mt)
        #pragma unroll
        for (int nt = 0; nt < 2; ++nt)
            #pragma unroll
            for (int v = 0; v < 4; ++v) {
                int r = m0 + wm + mt * 16 + lh * 4 + v;
                int c = n0 + wn + nt * 16 + lr;
                float g = accg[mt][nt][v];
                float u = accu[mt][nt][v];
                float s = g / (1.f + __expf(-g));
                He[(size_t)r * INTER + c] = (__bf16)(s * u);
            }
}

// ---------- plain bf16 GEMM, C = A * Bt^T per expert (fp32 out) ----------
#define BN 128

__global__ void gemm_bt(const __bf16* __restrict__ A, const __bf16* __restrict__ Bt,
                        float* __restrict__ C, int M, int N, int K,
                        size_t sA, size_t sB, size_t sC) {
    __shared__ alignas(16) __bf16 As[BM * BK];
    __shared__ alignas(16) __bf16 Bs[BN * BK];

    const int tid  = threadIdx.x;
    const int wid  = tid >> 6;
    const int lane = tid & 63;
    const int lr   = lane & 15;
    const int lh   = lane >> 4;
    const int m0   = blockIdx.y * BM;
    const int n0   = blockIdx.x * BN;

    const __bf16* Ae = A  + (size_t)blockIdx.z * sA;
    const __bf16* Be = Bt + (size_t)blockIdx.z * sB;

    const int wm = (wid >> 1) * 64;
    const int wn = (wid & 1) * 64;

    floatx4 acc[4][4];
    #pragma unroll
    for (int i = 0; i < 4; ++i)
        #pragma unroll
        for (int j = 0; j < 4; ++j)
            acc[i][j] = floatx4{0.f, 0.f, 0.f, 0.f};

    const int segBase = wid * 2048;

    for (int kt = 0; kt < K; kt += BK) {
        #pragma unroll
        for (int c = 0; c < 2; ++c) {
            int L    = segBase + c * 1024 + lane * 16;
            int row  = L >> 6;
            int colb = L & 63;
            const char* gp = (const char*)(Ae + (size_t)(m0 + row) * K + kt) + colb;
            load_lds16(gp, (char*)As + segBase + c * 1024);
        }
        #pragma unroll
        for (int c = 0; c < 2; ++c) {
            int L    = segBase + c * 1024 + lane * 16;
            int row  = L >> 6;
            int colb = L & 63;
            const char* gp = (const char*)(Be + (size_t)(n0 + row) * K + kt) + colb;
            load_lds16(gp, (char*)Bs + segBase + c * 1024);
        }
        __syncthreads();

        bf16x8 a[4], b[4];
        #pragma unroll
        for (int mt = 0; mt < 4; ++mt)
            a[mt] = *(const bf16x8*)&As[(wm + mt * 16 + lr) * BK + lh * 8];
        #pragma unroll
        for (int nt = 0; nt < 4; ++nt)
            b[nt] = *(const bf16x8*)&Bs[(wn + nt * 16 + lr) * BK + lh * 8];

        #pragma unroll
        for (int mt = 0; mt < 4; ++mt)
            #pragma unroll
            for (int nt = 0; nt < 4; ++nt)
                acc[mt][nt] = __builtin_amdgcn_mfma_f32_16x16x32_bf16(
                    a[mt], b[nt], acc[mt][nt], 0, 0, 0);
        __syncthreads();
    }

    float* Ce = C + (size_t)blockIdx.z * sC;
    #pragma unroll
    for (int mt = 0; mt < 4; ++mt)
        #pragma unroll
        for (int nt = 0; nt < 4; ++nt)
            #pragma unroll
            for (int v = 0; v < 4; ++v) {
                int r = m0 + wm + mt * 16 + lh * 4 + v;
                int c = n0 + wn + nt * 16 + lr;
                Ce[(size_t)r * N + c] = acc[mt][nt][v];
            }
}

extern "C" void kernel_launch(void* const* d_in, const int* in_sizes, int n_in,
                              void* d_out, int out_size, void* d_ws, size_t ws_size,
                              hipStream_t stream) {
    const float* x   = (const float*)d_in[0];  // [E*T, D]
    const float* wgu = (const float*)d_in[1];  // [E, D, 2I]
    const float* wd  = (const float*)d_in[2];  // [E, I, D]
    float* out = (float*)d_out;                // [E*T, D] fp32

    constexpr size_t E = NUM_EXPERTS, T = TOKENS, D = HIDDEN, I = INTER;

    // Workspace (bytes):
    //   [0,          33554432)  Xb   (E*T*D bf16)
    //   [33554432,  134217728)  H    (E*T*I bf16)
    //   [134217728, 536870912)  WguT (E*2I*D bf16); WdT (E*D*I bf16) aliases
    //                           its first half after gemm1 is done.
    char* ws = (char*)d_ws;
    __bf16* Xb   = (__bf16*)ws;
    __bf16* H    = (__bf16*)(ws + 33554432);
    __bf16* WguT = (__bf16*)(ws + 134217728);
    __bf16* WdT  = (__bf16*)(ws + 134217728);  // alias: WguT dead before t2

    // 1) tokens fp32 -> bf16
    cvt_f32_bf16<<<dim3(16384), dim3(256), 0, stream>>>(x, Xb, E * T * D);

    // 2) w_gate_up [E][D][2I] -> WguT [E][2I][D] bf16
    transpose_cvt<<<dim3(2 * I / 64, D / 64, E), dim3(256), 0, stream>>>(
        wgu, WguT, (int)D, (int)(2 * I));

    // 3) GEMM1 + silu: H[e] = silu(Xb Wg^T) * (Xb Wu^T)  [T x I] bf16
    gemm1_silu<<<dim3(I / 64, T / BM, E), dim3(256), 0, stream>>>(Xb, WguT, H);

    // 4) w_down [E][I][D] -> WdT [E][D][I] bf16
    transpose_cvt<<<dim3(D / 64, I / 64, E), dim3(256), 0, stream>>>(
        wd, WdT, (int)I, (int)D);

    // 5) GEMM2: out[e] = H[e] (T x I) * WdT[e]^T -> [T x D] fp32
    gemm_bt<<<dim3(D / BN, T / BM, E), dim3(256), 0, stream>>>(
        H, WdT, out, (int)T, (int)D, (int)I, T * I, D * I, T * D);
}